// Round 5
// baseline (3355.770 us; speedup 1.0000x reference)
//
#include <hip/hip_runtime.h>
#include <math.h>

// Problem constants
#define BN 16
#define CIN 64
#define HH 128
#define WW 128
#define HWSZ (HH*WW)          // 16384
#define NC 80
#define KK 100

// Workspace layout (in floats)
#define WS_WT1   0
#define WT1_SZ   (3*64*9*64)                 // 110592
#define WS_CLS   (WS_WT1 + WT1_SZ)
#define CLS_SZ   (BN*NC*HWSZ)                // 20,971,520
#define WS_REG   (WS_CLS + CLS_SZ)
#define REG_SZ   (BN*2*HWSZ)
#define WS_WH    (WS_REG + REG_SZ)
#define WH_SZ    (BN*2*HWSZ)
#define WS_SC    (WS_WH + WH_SZ)             // scores_all (destroyed by k_select)
#define SC_SZ    (BN*HWSZ)
#define WS_CAT   (WS_SC + SC_SZ)             // int cats_all
#define CAT_SZ   (BN*HWSZ)

// ---------------------------------------------------------------------------
// Kernel 0: transpose conv1 weights OIHW(co,ci,ky,kx) -> [br][ci][k][co]
// ---------------------------------------------------------------------------
__global__ void k_transpose_w1(const float* __restrict__ cw,
                               const float* __restrict__ rw,
                               const float* __restrict__ ww,
                               float* __restrict__ wt) {
    int idx = blockIdx.x * 256 + threadIdx.x;
    if (idx >= 3*64*9*64) return;
    int co = idx & 63;
    int k  = (idx >> 6) % 9;
    int ci = (idx / 576) & 63;
    int br = idx / (576*64);
    const float* src = (br == 0) ? cw : (br == 1 ? rw : ww);
    wt[idx] = src[(co*64 + ci)*9 + k];
}

// ---------------------------------------------------------------------------
// Kernel 1: fused conv1(3x3)+bias+ReLU -> conv2(1x1)+bias+activation.
// grid (y-pair=64, b=16, branch=3), block 128 (one px, TWO rows per thread).
// r4 post-mortem: VALUBusy 69%, ~31% stalls = loop-carried input loads with
// zero prefetch distance at 2 waves/SIMD (LLVM doesn't modulo-schedule).
// Fix: manual 2x unroll + ping-pong iv buffers -> loads for ci+1 issue before
// the 1152-FMA block for ci (~2300 issue-cycles of latency cover).
// FMA order per output unchanged -> absmax stays 0.
// No min-waves bound (r2 lesson: forcing occupancy bloats instruction count).
// ---------------------------------------------------------------------------
__global__ __launch_bounds__(128) void k_conv_branch(
    const float* __restrict__ x, const float* __restrict__ wt1,
    const float* __restrict__ b1c, const float* __restrict__ b1r, const float* __restrict__ b1w,
    const float* __restrict__ w2c, const float* __restrict__ w2r, const float* __restrict__ w2w,
    const float* __restrict__ b2c, const float* __restrict__ b2r, const float* __restrict__ b2w,
    float* __restrict__ cls_o, float* __restrict__ reg_o, float* __restrict__ wh_o)
{
    const int y0 = blockIdx.x * 2;    // output rows y0, y0+1
    const int b  = blockIdx.y;
    const int br = blockIdx.z;
    const int px = threadIdx.x;       // 0..127

    const float* wtb = wt1 + __builtin_amdgcn_readfirstlane(br*36864);

    float acc0[64], acc1[64];
    #pragma unroll
    for (int i = 0; i < 64; i++) { acc0[i] = 0.f; acc1[i] = 0.f; }

    const bool ytop = (y0 > 0);       // row y0-1 valid (block-uniform)
    const bool ybot = (y0 < 126);     // row y0+2 valid (block-uniform)
    const bool xl   = (px > 0);
    const bool xr   = (px < 127);

    const float* xb = x + ((size_t)(b*64)*128 + y0)*128 + px;

    // iv[r][c]: input rows y0-1+r (r=0..3), cols px-1+c (c=0..2)
    #define LOAD_IV(dst, ci_) do {                                   \
        const float* rp = xb + (size_t)(ci_)*HWSZ;                   \
        dst[0][0] = (ytop && xl) ? rp[-129] : 0.f;                   \
        dst[0][1] =  ytop        ? rp[-128] : 0.f;                   \
        dst[0][2] = (ytop && xr) ? rp[-127] : 0.f;                   \
        dst[1][0] =  xl          ? rp[-1]   : 0.f;                   \
        dst[1][1] =                rp[0];                            \
        dst[1][2] =  xr          ? rp[1]    : 0.f;                   \
        dst[2][0] =  xl          ? rp[127]  : 0.f;                   \
        dst[2][1] =                rp[128];                          \
        dst[2][2] =  xr          ? rp[129]  : 0.f;                   \
        dst[3][0] = (ybot && xl) ? rp[255]  : 0.f;                   \
        dst[3][1] =  ybot        ? rp[256]  : 0.f;                   \
        dst[3][2] = (ybot && xr) ? rp[257]  : 0.f;                   \
    } while (0)

    #define FMA_BLK(src, ci_) do {                                   \
        const float* wci = wtb + __builtin_amdgcn_readfirstlane((ci_)*576); \
        _Pragma("unroll")                                            \
        for (int k = 0; k < 9; k++) {                                \
            const int dy = k/3, dx = k%3;                            \
            float v0 = src[dy][dx];                                  \
            float v1 = src[dy+1][dx];                                \
            const float* wk = wci + k*64;                            \
            _Pragma("unroll")                                        \
            for (int c = 0; c < 64; c++) {                           \
                float w = wk[c];                                     \
                acc0[c] += v0 * w;                                   \
                acc1[c] += v1 * w;                                   \
            }                                                        \
        }                                                            \
    } while (0)

    float ivA[4][3], ivB[4][3];
    LOAD_IV(ivA, 0);
    for (int ci = 0; ci < 64; ci += 2) {
        LOAD_IV(ivB, ci + 1);
        FMA_BLK(ivA, ci);
        int cn = (ci + 2 < 64) ? ci + 2 : 63;   // last prefetch harmless dup
        LOAD_IV(ivA, cn);
        FMA_BLK(ivB, ci + 1);
    }
    #undef LOAD_IV
    #undef FMA_BLK

    // bias + ReLU (b1 uniform -> scalar loads)
    const float* b1 = (br == 0) ? b1c : (br == 1 ? b1r : b1w);
    #pragma unroll
    for (int c = 0; c < 64; c++) {
        acc0[c] = fmaxf(acc0[c] + b1[c], 0.f);
        acc1[c] = fmaxf(acc1[c] + b1[c], 0.f);
    }

    if (br == 0) {
        float* outp = cls_o + (size_t)b*80*HWSZ + y0*128 + px;
        for (int co2 = 0; co2 < 80; co2++) {
            const float* w2row = w2c + __builtin_amdgcn_readfirstlane(co2*64);
            float s0a=0.f, s1a=0.f, s2a=0.f, s3a=0.f;
            float s0b=0.f, s1b=0.f, s2b=0.f, s3b=0.f;
            #pragma unroll
            for (int c = 0; c < 64; c += 4) {
                float w0=w2row[c+0], w1=w2row[c+1], w2v=w2row[c+2], w3=w2row[c+3];
                s0a += acc0[c+0]*w0; s1a += acc0[c+1]*w1;
                s2a += acc0[c+2]*w2v; s3a += acc0[c+3]*w3;
                s0b += acc1[c+0]*w0; s1b += acc1[c+1]*w1;
                s2b += acc1[c+2]*w2v; s3b += acc1[c+3]*w3;
            }
            float bb = b2c[co2];
            float sa = ((s0a+s1a)+(s2a+s3a)) + bb;
            float sb = ((s0b+s1b)+(s2b+s3b)) + bb;
            outp[(size_t)co2*HWSZ]       = 1.f/(1.f + expf(-sa));
            outp[(size_t)co2*HWSZ + 128] = 1.f/(1.f + expf(-sb));
        }
    } else {
        const float* w2  = (br == 1) ? w2r : w2w;
        const float* b2  = (br == 1) ? b2r : b2w;
        float* outp      = (br == 1) ? reg_o : wh_o;
        #pragma unroll
        for (int co2 = 0; co2 < 2; co2++) {
            const float* w2row = w2 + co2*64;
            float s0a=0.f, s1a=0.f, s2a=0.f, s3a=0.f;
            float s0b=0.f, s1b=0.f, s2b=0.f, s3b=0.f;
            #pragma unroll
            for (int c = 0; c < 64; c += 4) {
                float w0=w2row[c+0], w1=w2row[c+1], w2v=w2row[c+2], w3=w2row[c+3];
                s0a += acc0[c+0]*w0; s1a += acc0[c+1]*w1;
                s2a += acc0[c+2]*w2v; s3a += acc0[c+3]*w3;
                s0b += acc1[c+0]*w0; s1b += acc1[c+1]*w1;
                s2b += acc1[c+2]*w2v; s3b += acc1[c+3]*w3;
            }
            float bb = b2[co2];
            float sa = ((s0a+s1a)+(s2a+s3a)) + bb;
            float sb = ((s0b+s1b)+(s2b+s3b)) + bb;
            float oa = (br == 1) ? (1.f/(1.f + expf(-sa))) : expf(sa);
            float ob = (br == 1) ? (1.f/(1.f + expf(-sb))) : expf(sb);
            float* orow = outp + ((size_t)(b*2 + co2))*HWSZ + y0*128 + px;
            orow[0]   = oa;
            orow[128] = ob;
        }
    }
}

// ---------------------------------------------------------------------------
// Kernel 2: 3x3 peak mask + max/argmax over classes — barrier-free.
// grid (32, 16), block 256 = 4 waves; wave w owns row y = bx*4+w,
// lane l owns px {2l, 2l+1}. Horizontal 3-max via shfl (no LDS, no barrier).
// ---------------------------------------------------------------------------
__global__ __launch_bounds__(256) void k_peaks(const float* __restrict__ cls,
                                               float* __restrict__ sc,
                                               int* __restrict__ cat) {
    const int b  = blockIdx.y;
    const int wv = threadIdx.x >> 6;
    const int l  = threadIdx.x & 63;
    const int y  = blockIdx.x * 4 + wv;
    const int p0 = l * 2;
    const bool yt = (y > 0), yb = (y < 127);
    float best0 = -1.f, best1 = -1.f;
    int bc0 = 0, bc1 = 0;
    for (int c = 0; c < 80; c++) {
        const float* pl = cls + (size_t)(b*80 + c)*HWSZ + y*128 + p0;
        float2 cur = *(const float2*)pl;
        float2 tp  = yt ? *(const float2*)(pl - 128) : make_float2(-1e30f, -1e30f);
        float2 bt  = yb ? *(const float2*)(pl + 128) : make_float2(-1e30f, -1e30f);
        float vm0 = fmaxf(cur.x, fmaxf(tp.x, bt.x));
        float vm1 = fmaxf(cur.y, fmaxf(tp.y, bt.y));
        float lft = __shfl_up(vm1, 1);   if (l == 0)  lft = -1e30f;
        float rgt = __shfl_down(vm0, 1); if (l == 63) rgt = -1e30f;
        float m0 = fmaxf(lft, fmaxf(vm0, vm1));
        float m1 = fmaxf(vm0, fmaxf(vm1, rgt));
        float k0 = (cur.x == m0) ? cur.x : 0.f;
        float k1 = (cur.y == m1) ? cur.y : 0.f;
        if (k0 > best0) { best0 = k0; bc0 = c; }   // strict > == first-max
        if (k1 > best1) { best1 = k1; bc1 = c; }
    }
    int o = b*HWSZ + y*128 + p0;
    *(float2*)&sc[o] = make_float2(best0, best1);
    *(int2*)&cat[o]  = make_int2(bc0, bc1);
}

// ---------------------------------------------------------------------------
// Kernel 3: fused per-batch top-100 + box decode + NMS + all outputs.
// grid 16, block 256. Destroys sc.
// ---------------------------------------------------------------------------
__global__ void k_select(float* __restrict__ sc, const int* __restrict__ cats,
                         const float* __restrict__ regp, const float* __restrict__ whp,
                         float* __restrict__ out) {
    const int b   = blockIdx.x;
    const int tid = threadIdx.x;
    float* scb = sc + (size_t)b*HWSZ;

    __shared__ float cmax[64];
    __shared__ int   cidx[64];
    __shared__ int   s_inds[KK];
    __shared__ float s_vals[KK];
    __shared__ float X1[KK], Y1[KK], X2[KK], Y2[KK], AR[KK];

    // ---- Phase A: per-chunk max (value desc, first index) ----
    {
        int c = tid >> 2, q = tid & 3;
        int base = c*256 + q*64;
        float bv = -1e30f; int bi = base;
        for (int e = 0; e < 64; e++) {
            float v = scb[base + e];
            if (v > bv) { bv = v; bi = base + e; }   // ascending: keeps first
        }
        #pragma unroll
        for (int off = 1; off <= 2; off <<= 1) {
            float ov = __shfl_xor(bv, off);
            int   oi = __shfl_xor(bi, off);
            if (ov > bv || (ov == bv && oi < bi)) { bv = ov; bi = oi; }
        }
        if (q == 0) { cmax[c] = bv; cidx[c] = bi; }
    }
    __syncthreads();

    // ---- Phase B: 100 selections, wave 0 only ----
    if (tid < 64) {
        const int l = tid;
        float v = cmax[l]; int ix = cidx[l];
        for (int it = 0; it < KK; it++) {
            float rv = v; int ri = ix;
            #pragma unroll
            for (int off = 32; off >= 1; off >>= 1) {
                float ov = __shfl_down(rv, off);
                int   oi = __shfl_down(ri, off);
                if (ov > rv || (ov == rv && oi < ri)) { rv = ov; ri = oi; }
            }
            float fv = __shfl(rv, 0);
            int   fi = __shfl(ri, 0);
            if (l == 0) { s_inds[it] = fi; s_vals[it] = fv; scb[fi] = -1e30f; }
            int wc = fi >> 8;                 // winning chunk
            int eb = wc*256 + l*4;
            float nv = -1e30f; int ni = eb;
            #pragma unroll
            for (int r = 0; r < 4; r++) {
                float u = scb[eb + r];
                if (u > nv) { nv = u; ni = eb + r; }
            }
            #pragma unroll
            for (int off = 32; off >= 1; off >>= 1) {
                float ov = __shfl_down(nv, off);
                int   oi = __shfl_down(ni, off);
                if (ov > nv || (ov == nv && oi < ni)) { nv = ov; ni = oi; }
            }
            float cv = __shfl(nv, 0);
            int   ci2 = __shfl(ni, 0);
            if (l == wc) { v = cv; ix = ci2; }
        }
    }
    __syncthreads();

    // ---- Phase C: decode boxes for the 100 selections ----
    if (tid < KK) {
        int ind   = s_inds[tid];
        float scv = s_vals[tid];
        const float* rb = regp + (size_t)b*2*HWSZ;
        const float* wb = whp  + (size_t)b*2*HWSZ;
        float r0 = rb[ind], r1 = rb[HWSZ + ind];
        float w0 = wb[ind], w1 = wb[HWSZ + ind];
        float ctx = (float)(ind & 127) + r0;
        float cty = (float)(ind >> 7) + r1;
        float x1 = (ctx - w0*0.5f)*4.f, y1 = (cty - w1*0.5f)*4.f;
        float x2 = (ctx + w0*0.5f)*4.f, y2 = (cty + w1*0.5f)*4.f;
        size_t bo = ((size_t)b*KK + tid)*4;
        out[bo+0] = x1; out[bo+1] = y1; out[bo+2] = x2; out[bo+3] = y2;
        out[BN*KK*4 + b*KK + tid]         = (float)cats[(size_t)b*HWSZ + ind];
        out[BN*KK*4 + BN*KK + b*KK + tid] = scv;
        X1[tid] = x1; Y1[tid] = y1; X2[tid] = x2; Y2[tid] = y2;
        AR[tid] = (x2 - x1)*(y2 - y1);
    }
    __syncthreads();

    // ---- Phase D: NMS in wave 0, no barriers ----
    if (tid < 64) {
        const int l = tid;
        float x1a = X1[l], y1a = Y1[l], x2a = X2[l], y2a = Y2[l], ara = AR[l];
        int   ka  = (s_vals[l] > 0.2f) ? 1 : 0;
        float x1b = 0, y1b = 0, x2b = 0, y2b = 0, arb = 0;
        int   kb  = 0;
        if (l < KK - 64) {
            x1b = X1[64+l]; y1b = Y1[64+l]; x2b = X2[64+l]; y2b = Y2[64+l];
            arb = AR[64+l];
            kb  = (s_vals[64+l] > 0.2f) ? 1 : 0;
        }
        for (int i = 0; i < KK; i++) {
            float jx1, jy1, jx2, jy2, jar; int jk;
            if (i < 64) {
                jx1 = __shfl(x1a, i); jy1 = __shfl(y1a, i);
                jx2 = __shfl(x2a, i); jy2 = __shfl(y2a, i);
                jar = __shfl(ara, i); jk  = __shfl(ka,  i);
            } else {
                int li = i - 64;
                jx1 = __shfl(x1b, li); jy1 = __shfl(y1b, li);
                jx2 = __shfl(x2b, li); jy2 = __shfl(y2b, li);
                jar = __shfl(arb, li); jk  = __shfl(kb,  li);
            }
            if (jk) {
                if (ka && l > i) {
                    float iw = fminf(jx2, x2a) - fmaxf(jx1, x1a); iw = iw > 0.f ? iw : 0.f;
                    float ih = fminf(jy2, y2a) - fmaxf(jy1, y1a); ih = ih > 0.f ? ih : 0.f;
                    float inter = iw*ih;
                    float iou = inter / (jar + ara - inter + 1e-9f);
                    if (iou > 0.5f) ka = 0;
                }
                if (kb && (64 + l) > i) {
                    float iw = fminf(jx2, x2b) - fmaxf(jx1, x1b); iw = iw > 0.f ? iw : 0.f;
                    float ih = fminf(jy2, y2b) - fmaxf(jy1, y1b); ih = ih > 0.f ? ih : 0.f;
                    float inter = iw*ih;
                    float iou = inter / (jar + arb - inter + 1e-9f);
                    if (iou > 0.5f) kb = 0;
                }
            }
        }
        int koff = BN*KK*4 + 2*BN*KK;
        out[koff + b*KK + l] = ka ? 1.f : 0.f;
        if (l < KK - 64) out[koff + b*KK + 64 + l] = kb ? 1.f : 0.f;
    }
}

// ---------------------------------------------------------------------------
extern "C" void kernel_launch(void* const* d_in, const int* in_sizes, int n_in,
                              void* d_out, int out_size, void* d_ws, size_t ws_size,
                              hipStream_t stream) {
    const float* x      = (const float*)d_in[0];
    const float* cls_w1 = (const float*)d_in[1];
    const float* cls_b1 = (const float*)d_in[2];
    const float* cls_w2 = (const float*)d_in[3];
    const float* cls_b2 = (const float*)d_in[4];
    const float* reg_w1 = (const float*)d_in[5];
    const float* reg_b1 = (const float*)d_in[6];
    const float* reg_w2 = (const float*)d_in[7];
    const float* reg_b2 = (const float*)d_in[8];
    const float* wh_w1  = (const float*)d_in[9];
    const float* wh_b1  = (const float*)d_in[10];
    const float* wh_w2  = (const float*)d_in[11];
    const float* wh_b2  = (const float*)d_in[12];

    float* ws   = (float*)d_ws;
    float* wt1  = ws + WS_WT1;
    float* clsb = ws + WS_CLS;
    float* regb = ws + WS_REG;
    float* whb  = ws + WS_WH;
    float* scw  = ws + WS_SC;
    int*   cat  = (int*)(ws + WS_CAT);
    float* out  = (float*)d_out;

    k_transpose_w1<<<(WT1_SZ + 255)/256, 256, 0, stream>>>(cls_w1, reg_w1, wh_w1, wt1);
    k_conv_branch<<<dim3(64, 16, 3), 128, 0, stream>>>(
        x, wt1, cls_b1, reg_b1, wh_b1, cls_w2, reg_w2, wh_w2,
        cls_b2, reg_b2, wh_b2, clsb, regb, whb);
    k_peaks<<<dim3(32, 16), 256, 0, stream>>>(clsb, scw, cat);
    k_select<<<16, 256, 0, stream>>>(scw, cat, regb, whb, out);
}

// Round 6
// 1058.630 us; speedup vs baseline: 3.1699x; 3.1699x over previous
//
#include <hip/hip_runtime.h>
#include <math.h>

// Problem constants
#define BN 16
#define HWSZ 16384
#define NC 80
#define KK 100

typedef _Float16 f16;
typedef _Float16 f16x8 __attribute__((ext_vector_type(8)));
typedef float    f32x4 __attribute__((ext_vector_type(4)));
typedef unsigned int uint;

// ---- workspace layout (float units) ----
#define WS_CLS   0
#define CLS_SZ   (BN*NC*HWSZ)                   // 20,971,520
#define WS_REG   (WS_CLS + CLS_SZ)
#define REG_SZ   (BN*2*HWSZ)
#define WS_WH    (WS_REG + REG_SZ)
#define WH_SZ    (BN*2*HWSZ)
#define WS_SC    (WS_WH + WH_SZ)
#define SC_SZ    (BN*HWSZ)
#define WS_CAT   (WS_SC + SC_SZ)
#define CAT_SZ   (BN*HWSZ)
#define WS_W1H   (WS_CAT + CAT_SZ)             // f16: 3*9*64*64 = 110592 -> 55296 floats
#define W1F      (110592/2)
#define WS_W1L   (WS_W1H + W1F)
#define WS_W2H   (WS_W1L + W1F)                // f16: 84*64 = 5376 -> 2688 floats
#define W2F      (5376/2)
#define WS_W2L   (WS_W2H + W2F)

// scaling: x*16, w*256 -> acc = 4096*true; relu*16 for conv2 A.
#define SCL_X   16.0f
#define SCL_W   256.0f
#define INV_ACC (1.0f/4096.0f)

// ---------------------------------------------------------------------------
// Prep: split weights to fp16 hi/lo (scaled by 256).
// w1 layout [br][s=dy*3+dx][co][ci]; w2 rows: 0..79 cls, 80..81 reg, 82..83 wh.
// ---------------------------------------------------------------------------
__global__ void k_prep(const float* __restrict__ cw1, const float* __restrict__ rw1,
                       const float* __restrict__ ww1, const float* __restrict__ cw2,
                       const float* __restrict__ rw2, const float* __restrict__ ww2,
                       f16* __restrict__ w1h, f16* __restrict__ w1l,
                       f16* __restrict__ w2h, f16* __restrict__ w2l) {
    int idx = blockIdx.x * 256 + threadIdx.x;
    if (idx < 3*9*64*64) {
        int ci = idx & 63, co = (idx >> 6) & 63;
        int s  = (idx >> 12) % 9, br = idx / 36864;
        const float* src = (br == 0) ? cw1 : (br == 1 ? rw1 : ww1);
        float v = src[(co*64 + ci)*9 + s] * SCL_W;
        f16 h = (f16)v;
        w1h[idx] = h; w1l[idx] = (f16)(v - (float)h);
    }
    int j = idx - 3*9*64*64;
    if (j >= 0 && j < 84*64) {
        int ci = j & 63, row = j >> 6;
        float v;
        if (row < 80)      v = cw2[row*64 + ci];
        else if (row < 82) v = rw2[(row-80)*64 + ci];
        else               v = ww2[(row-82)*64 + ci];
        v *= SCL_W;
        f16 h = (f16)v;
        w2h[j] = h; w2l[j] = (f16)(v - (float)h);
    }
}

// ---------------------------------------------------------------------------
// Fused MFMA conv: conv1(3x3,64->64)+ReLU -> conv2(1x1) for all 3 branches.
// grid (y=128, b=16), block 256 (4 waves). Wave w: px [32w,32w+32), all co.
// fp16 hi/lo split, 3 MFMA terms per pair (fp32-grade precision; scaled to
// keep lo-planes out of fp16 subnormal range).
// LDS 59,904 B -> 2 blocks/CU.
// ---------------------------------------------------------------------------
__global__ __launch_bounds__(256) void k_conv(
    const float* __restrict__ x,
    const f16* __restrict__ w1h, const f16* __restrict__ w1l,
    const f16* __restrict__ w2h, const f16* __restrict__ w2l,
    const float* __restrict__ b1c, const float* __restrict__ b1r, const float* __restrict__ b1w,
    const float* __restrict__ b2c, const float* __restrict__ b2r, const float* __restrict__ b2w,
    float* __restrict__ cls_o, float* __restrict__ reg_o, float* __restrict__ wh_o)
{
    __shared__ char smem[59904] __attribute__((aligned(16)));
    // phase 1: one input row [130 px][stride 40, 32 ci] hi/lo + B tile [64 co][40]
    f16* Ah = (f16*)(smem);             // 10,400 B
    f16* Al = (f16*)(smem + 10400);     // 10,400 B
    f16* Bh = (f16*)(smem + 20800);     //  5,120 B
    f16* Bl = (f16*)(smem + 25920);     //  5,120 B
    // phase 2 (aliases): relu [128 px][stride 72, 64 c] hi/lo + B2 [80][72]
    f16* Rh  = (f16*)(smem);            // 18,432 B
    f16* Rl  = (f16*)(smem + 18432);    // 18,432 B
    f16* B2h = (f16*)(smem + 36864);    // 11,520 B
    f16* B2l = (f16*)(smem + 48384);    // 11,520 B

    const int y = blockIdx.x, b = blockIdx.y;
    const int tid = threadIdx.x;
    const int w = tid >> 6, lane = tid & 63;
    const int l15 = lane & 15, quad = lane >> 4;
    const int wbase = w * 32;

    f32x4 acc[3][2][4];
    #pragma unroll
    for (int br = 0; br < 3; br++)
        #pragma unroll
        for (int m = 0; m < 2; m++)
            #pragma unroll
            for (int n = 0; n < 4; n++)
                acc[br][m][n] = (f32x4){0.f, 0.f, 0.f, 0.f};

    // ======================= conv1 =======================
    for (int chunk = 0; chunk < 2; chunk++) {
        for (int r = 0; r < 3; r++) {
            __syncthreads();                       // protect A region
            // stage input row gy = y-1+r, 32 ci x 128 px, transposed to [px][ci]
            const int gy = y - 1 + r;
            const bool ok = (gy >= 0) && (gy <= 127);
            for (int e = tid; e < 4096; e += 256) {
                int px = e & 127, ci = e >> 7;
                float v = 0.f;
                if (ok)
                    v = x[(((size_t)(b*64 + chunk*32 + ci))*128 + gy)*128 + px] * SCL_X;
                f16 h = (f16)v;
                int ai = (px + 1)*40 + ci;
                Ah[ai] = h; Al[ai] = (f16)(v - (float)h);
            }
            if (tid < 64) {                        // zero px guards (slots 0, 129)
                int side = tid >> 5, ci = tid & 31;
                int ai = (side ? 129 : 0)*40 + ci;
                Ah[ai] = (f16)0.f; Al[ai] = (f16)0.f;
            }
            __syncthreads();

            for (int dx = 0; dx < 3; dx++) {
                const int s = r*3 + dx;
                // A-fragments for this shift (held across branches)
                f16x8 ah[2], al[2];
                #pragma unroll
                for (int m = 0; m < 2; m++) {
                    int ai = (wbase + m*16 + l15 + dx)*40 + quad*8;
                    ah[m] = *(const f16x8*)&Ah[ai];
                    al[m] = *(const f16x8*)&Al[ai];
                }
                #pragma unroll
                for (int br = 0; br < 3; br++) {
                    __syncthreads();               // protect B region
                    {   // stage B(chunk, s, br): 64 co x 32 ci (uint pairs)
                        const f16* sh = w1h + ((size_t)(br*9 + s)*64)*64 + chunk*32;
                        const f16* sl = w1l + ((size_t)(br*9 + s)*64)*64 + chunk*32;
                        for (int e = tid; e < 1024; e += 256) {
                            int co = e >> 4, c2 = (e & 15)*2;
                            *(uint*)&Bh[co*40 + c2] = *(const uint*)&sh[co*64 + c2];
                            *(uint*)&Bl[co*40 + c2] = *(const uint*)&sl[co*64 + c2];
                        }
                    }
                    __syncthreads();
                    #pragma unroll
                    for (int n = 0; n < 4; n++) {
                        int bi = (n*16 + l15)*40 + quad*8;
                        f16x8 bh = *(const f16x8*)&Bh[bi];
                        f16x8 bl = *(const f16x8*)&Bl[bi];
                        #pragma unroll
                        for (int m = 0; m < 2; m++) {
                            acc[br][m][n] = __builtin_amdgcn_mfma_f32_16x16x32_f16(ah[m], bh, acc[br][m][n], 0, 0, 0);
                            acc[br][m][n] = __builtin_amdgcn_mfma_f32_16x16x32_f16(ah[m], bl, acc[br][m][n], 0, 0, 0);
                            acc[br][m][n] = __builtin_amdgcn_mfma_f32_16x16x32_f16(al[m], bh, acc[br][m][n], 0, 0, 0);
                        }
                    }
                }
            }
        }
    }

    // ======================= relu + conv2 per branch =======================
    #pragma unroll
    for (int br = 0; br < 3; br++) {
        const float* b1 = (br == 0) ? b1c : (br == 1 ? b1r : b1w);
        float b1v[4];
        #pragma unroll
        for (int n = 0; n < 4; n++) b1v[n] = b1[n*16 + l15];
        __syncthreads();                           // protect R/B2 regions
        // write relu1 (C-layout -> A-layout via LDS), scaled by 16
        #pragma unroll
        for (int m = 0; m < 2; m++)
            #pragma unroll
            for (int n = 0; n < 4; n++)
                #pragma unroll
                for (int rg = 0; rg < 4; rg++) {
                    float t = fmaxf(acc[br][m][n][rg]*INV_ACC + b1v[n], 0.f) * SCL_X;
                    f16 h = (f16)t;
                    int px = wbase + m*16 + quad*4 + rg;
                    int co = n*16 + l15;
                    Rh[px*72 + co] = h;
                    Rl[px*72 + co] = (f16)(t - (float)h);
                }
        // stage B2
        {
            const int rows   = (br == 0) ? 80 : 16;
            const int rowoff = (br == 0) ? 0 : (br == 1 ? 80 : 82);
            for (int e = tid; e < rows*32; e += 256) {
                int row = e >> 5, c2 = (e & 31)*2;
                uint hv = 0, lv = 0;
                if (br == 0 || row < 2) {
                    hv = *(const uint*)&w2h[(rowoff + row)*64 + c2];
                    lv = *(const uint*)&w2l[(rowoff + row)*64 + c2];
                }
                *(uint*)&B2h[row*72 + c2] = hv;
                *(uint*)&B2l[row*72 + c2] = lv;
            }
        }
        __syncthreads();

        const int NT = (br == 0) ? 5 : 1;
        f32x4 a2[5][2];
        #pragma unroll
        for (int n = 0; n < 5; n++)
            #pragma unroll
            for (int m = 0; m < 2; m++)
                a2[n][m] = (f32x4){0.f, 0.f, 0.f, 0.f};

        #pragma unroll
        for (int kc = 0; kc < 64; kc += 32) {
            f16x8 xh[2], xl[2];
            #pragma unroll
            for (int m = 0; m < 2; m++) {
                int ai = (wbase + m*16 + l15)*72 + kc + quad*8;
                xh[m] = *(const f16x8*)&Rh[ai];
                xl[m] = *(const f16x8*)&Rl[ai];
            }
            #pragma unroll
            for (int n = 0; n < 5; n++) {
                if (n >= NT) break;
                int bi = (n*16 + l15)*72 + kc + quad*8;
                f16x8 bh = *(const f16x8*)&B2h[bi];
                f16x8 bl = *(const f16x8*)&B2l[bi];
                #pragma unroll
                for (int m = 0; m < 2; m++) {
                    a2[n][m] = __builtin_amdgcn_mfma_f32_16x16x32_f16(xh[m], bh, a2[n][m], 0, 0, 0);
                    a2[n][m] = __builtin_amdgcn_mfma_f32_16x16x32_f16(xh[m], bl, a2[n][m], 0, 0, 0);
                    a2[n][m] = __builtin_amdgcn_mfma_f32_16x16x32_f16(xl[m], bh, a2[n][m], 0, 0, 0);
                }
            }
        }

        if (br == 0) {
            #pragma unroll
            for (int n = 0; n < 5; n++) {
                int co2 = n*16 + l15;
                float bb = b2c[co2];
                #pragma unroll
                for (int m = 0; m < 2; m++)
                    #pragma unroll
                    for (int rg = 0; rg < 4; rg++) {
                        float sv = a2[n][m][rg]*INV_ACC + bb;
                        int px = wbase + m*16 + quad*4 + rg;
                        cls_o[((size_t)(b*80 + co2)*128 + y)*128 + px] = 1.f/(1.f + expf(-sv));
                    }
            }
        } else {
            if (l15 < 2) {
                const float* b2 = (br == 1) ? b2r : b2w;
                float* outp     = (br == 1) ? reg_o : wh_o;
                float bb = b2[l15];
                #pragma unroll
                for (int m = 0; m < 2; m++)
                    #pragma unroll
                    for (int rg = 0; rg < 4; rg++) {
                        float sv = a2[0][m][rg]*INV_ACC + bb;
                        float o  = (br == 1) ? (1.f/(1.f + expf(-sv))) : expf(sv);
                        int px = wbase + m*16 + quad*4 + rg;
                        outp[((size_t)(b*2 + l15)*128 + y)*128 + px] = o;
                    }
            }
        }
    }
}

// ---------------------------------------------------------------------------
// 3x3 peak mask + max/argmax over classes — barrier-free (r5, verified).
// ---------------------------------------------------------------------------
__global__ __launch_bounds__(256) void k_peaks(const float* __restrict__ cls,
                                               float* __restrict__ sc,
                                               int* __restrict__ cat) {
    const int b  = blockIdx.y;
    const int wv = threadIdx.x >> 6;
    const int l  = threadIdx.x & 63;
    const int y  = blockIdx.x * 4 + wv;
    const int p0 = l * 2;
    const bool yt = (y > 0), yb = (y < 127);
    float best0 = -1.f, best1 = -1.f;
    int bc0 = 0, bc1 = 0;
    for (int c = 0; c < 80; c++) {
        const float* pl = cls + (size_t)(b*80 + c)*HWSZ + y*128 + p0;
        float2 cur = *(const float2*)pl;
        float2 tp  = yt ? *(const float2*)(pl - 128) : make_float2(-1e30f, -1e30f);
        float2 bt  = yb ? *(const float2*)(pl + 128) : make_float2(-1e30f, -1e30f);
        float vm0 = fmaxf(cur.x, fmaxf(tp.x, bt.x));
        float vm1 = fmaxf(cur.y, fmaxf(tp.y, bt.y));
        float lft = __shfl_up(vm1, 1);   if (l == 0)  lft = -1e30f;
        float rgt = __shfl_down(vm0, 1); if (l == 63) rgt = -1e30f;
        float m0 = fmaxf(lft, fmaxf(vm0, vm1));
        float m1 = fmaxf(vm0, fmaxf(vm1, rgt));
        float k0 = (cur.x == m0) ? cur.x : 0.f;
        float k1 = (cur.y == m1) ? cur.y : 0.f;
        if (k0 > best0) { best0 = k0; bc0 = c; }   // strict > == first-max
        if (k1 > best1) { best1 = k1; bc1 = c; }
    }
    int o = b*HWSZ + y*128 + p0;
    *(float2*)&sc[o] = make_float2(best0, best1);
    *(int2*)&cat[o]  = make_int2(bc0, bc1);
}

// ---------------------------------------------------------------------------
// Fused per-batch top-100 + box decode + NMS + all outputs (r5, verified).
// ---------------------------------------------------------------------------
__global__ void k_select(float* __restrict__ sc, const int* __restrict__ cats,
                         const float* __restrict__ regp, const float* __restrict__ whp,
                         float* __restrict__ out) {
    const int b   = blockIdx.x;
    const int tid = threadIdx.x;
    float* scb = sc + (size_t)b*HWSZ;

    __shared__ float cmax[64];
    __shared__ int   cidx[64];
    __shared__ int   s_inds[KK];
    __shared__ float s_vals[KK];
    __shared__ float X1[KK], Y1[KK], X2[KK], Y2[KK], AR[KK];

    {   // Phase A: per-chunk max (value desc, first index)
        int c = tid >> 2, q = tid & 3;
        int base = c*256 + q*64;
        float bv = -1e30f; int bi = base;
        for (int e = 0; e < 64; e++) {
            float v = scb[base + e];
            if (v > bv) { bv = v; bi = base + e; }
        }
        #pragma unroll
        for (int off = 1; off <= 2; off <<= 1) {
            float ov = __shfl_xor(bv, off);
            int   oi = __shfl_xor(bi, off);
            if (ov > bv || (ov == bv && oi < bi)) { bv = ov; bi = oi; }
        }
        if (q == 0) { cmax[c] = bv; cidx[c] = bi; }
    }
    __syncthreads();

    if (tid < 64) {  // Phase B: 100 selections, wave 0
        const int l = tid;
        float v = cmax[l]; int ix = cidx[l];
        for (int it = 0; it < KK; it++) {
            float rv = v; int ri = ix;
            #pragma unroll
            for (int off = 32; off >= 1; off >>= 1) {
                float ov = __shfl_down(rv, off);
                int   oi = __shfl_down(ri, off);
                if (ov > rv || (ov == rv && oi < ri)) { rv = ov; ri = oi; }
            }
            float fv = __shfl(rv, 0);
            int   fi = __shfl(ri, 0);
            if (l == 0) { s_inds[it] = fi; s_vals[it] = fv; scb[fi] = -1e30f; }
            int wc = fi >> 8;
            int eb = wc*256 + l*4;
            float nv = -1e30f; int ni = eb;
            #pragma unroll
            for (int r = 0; r < 4; r++) {
                float u = scb[eb + r];
                if (u > nv) { nv = u; ni = eb + r; }
            }
            #pragma unroll
            for (int off = 32; off >= 1; off >>= 1) {
                float ov = __shfl_down(nv, off);
                int   oi = __shfl_down(ni, off);
                if (ov > nv || (ov == nv && oi < ni)) { nv = ov; ni = oi; }
            }
            float cv = __shfl(nv, 0);
            int   ci2 = __shfl(ni, 0);
            if (l == wc) { v = cv; ix = ci2; }
        }
    }
    __syncthreads();

    if (tid < KK) {  // Phase C: decode boxes
        int ind   = s_inds[tid];
        float scv = s_vals[tid];
        const float* rb = regp + (size_t)b*2*HWSZ;
        const float* wb = whp  + (size_t)b*2*HWSZ;
        float r0 = rb[ind], r1 = rb[HWSZ + ind];
        float w0 = wb[ind], w1 = wb[HWSZ + ind];
        float ctx = (float)(ind & 127) + r0;
        float cty = (float)(ind >> 7) + r1;
        float x1 = (ctx - w0*0.5f)*4.f, y1 = (cty - w1*0.5f)*4.f;
        float x2 = (ctx + w0*0.5f)*4.f, y2 = (cty + w1*0.5f)*4.f;
        size_t bo = ((size_t)b*KK + tid)*4;
        out[bo+0] = x1; out[bo+1] = y1; out[bo+2] = x2; out[bo+3] = y2;
        out[BN*KK*4 + b*KK + tid]         = (float)cats[(size_t)b*HWSZ + ind];
        out[BN*KK*4 + BN*KK + b*KK + tid] = scv;
        X1[tid] = x1; Y1[tid] = y1; X2[tid] = x2; Y2[tid] = y2;
        AR[tid] = (x2 - x1)*(y2 - y1);
    }
    __syncthreads();

    if (tid < 64) {  // Phase D: NMS in wave 0
        const int l = tid;
        float x1a = X1[l], y1a = Y1[l], x2a = X2[l], y2a = Y2[l], ara = AR[l];
        int   ka  = (s_vals[l] > 0.2f) ? 1 : 0;
        float x1b = 0, y1b = 0, x2b = 0, y2b = 0, arb = 0;
        int   kb  = 0;
        if (l < KK - 64) {
            x1b = X1[64+l]; y1b = Y1[64+l]; x2b = X2[64+l]; y2b = Y2[64+l];
            arb = AR[64+l];
            kb  = (s_vals[64+l] > 0.2f) ? 1 : 0;
        }
        for (int i = 0; i < KK; i++) {
            float jx1, jy1, jx2, jy2, jar; int jk;
            if (i < 64) {
                jx1 = __shfl(x1a, i); jy1 = __shfl(y1a, i);
                jx2 = __shfl(x2a, i); jy2 = __shfl(y2a, i);
                jar = __shfl(ara, i); jk  = __shfl(ka,  i);
            } else {
                int li = i - 64;
                jx1 = __shfl(x1b, li); jy1 = __shfl(y1b, li);
                jx2 = __shfl(x2b, li); jy2 = __shfl(y2b, li);
                jar = __shfl(arb, li); jk  = __shfl(kb,  li);
            }
            if (jk) {
                if (ka && l > i) {
                    float iw = fminf(jx2, x2a) - fmaxf(jx1, x1a); iw = iw > 0.f ? iw : 0.f;
                    float ih = fminf(jy2, y2a) - fmaxf(jy1, y1a); ih = ih > 0.f ? ih : 0.f;
                    float inter = iw*ih;
                    float iou = inter / (jar + ara - inter + 1e-9f);
                    if (iou > 0.5f) ka = 0;
                }
                if (kb && (64 + l) > i) {
                    float iw = fminf(jx2, x2b) - fmaxf(jx1, x1b); iw = iw > 0.f ? iw : 0.f;
                    float ih = fminf(jy2, y2b) - fmaxf(jy1, y1b); ih = ih > 0.f ? ih : 0.f;
                    float inter = iw*ih;
                    float iou = inter / (jar + arb - inter + 1e-9f);
                    if (iou > 0.5f) kb = 0;
                }
            }
        }
        int koff = BN*KK*4 + 2*BN*KK;
        out[koff + b*KK + l] = ka ? 1.f : 0.f;
        if (l < KK - 64) out[koff + b*KK + 64 + l] = kb ? 1.f : 0.f;
    }
}

// ---------------------------------------------------------------------------
extern "C" void kernel_launch(void* const* d_in, const int* in_sizes, int n_in,
                              void* d_out, int out_size, void* d_ws, size_t ws_size,
                              hipStream_t stream) {
    const float* x      = (const float*)d_in[0];
    const float* cls_w1 = (const float*)d_in[1];
    const float* cls_b1 = (const float*)d_in[2];
    const float* cls_w2 = (const float*)d_in[3];
    const float* cls_b2 = (const float*)d_in[4];
    const float* reg_w1 = (const float*)d_in[5];
    const float* reg_b1 = (const float*)d_in[6];
    const float* reg_w2 = (const float*)d_in[7];
    const float* reg_b2 = (const float*)d_in[8];
    const float* wh_w1  = (const float*)d_in[9];
    const float* wh_b1  = (const float*)d_in[10];
    const float* wh_w2  = (const float*)d_in[11];
    const float* wh_b2  = (const float*)d_in[12];

    float* ws   = (float*)d_ws;
    float* clsb = ws + WS_CLS;
    float* regb = ws + WS_REG;
    float* whb  = ws + WS_WH;
    float* scw  = ws + WS_SC;
    int*   cat  = (int*)(ws + WS_CAT);
    f16*   w1h  = (f16*)(ws + WS_W1H);
    f16*   w1l  = (f16*)(ws + WS_W1L);
    f16*   w2h  = (f16*)(ws + WS_W2H);
    f16*   w2l  = (f16*)(ws + WS_W2L);
    float* out  = (float*)d_out;

    k_prep<<<(3*9*64*64 + 84*64 + 255)/256, 256, 0, stream>>>(
        cls_w1, reg_w1, wh_w1, cls_w2, reg_w2, wh_w2, w1h, w1l, w2h, w2l);
    k_conv<<<dim3(128, 16), 256, 0, stream>>>(
        x, w1h, w1l, w2h, w2l, cls_b1, reg_b1, wh_b1,
        cls_b2, reg_b2, wh_b2, clsb, regb, whb);
    k_peaks<<<dim3(32, 16), 256, 0, stream>>>(clsb, scw, cat);
    k_select<<<16, 256, 0, stream>>>(scw, cat, regb, whb, out);
}

// Round 7
// 853.777 us; speedup vs baseline: 3.9305x; 1.2399x over previous
//
#include <hip/hip_runtime.h>
#include <math.h>

// Problem constants
#define BN 16
#define HWSZ 16384
#define NC 80
#define KK 100

typedef _Float16 f16;
typedef _Float16 f16x2 __attribute__((ext_vector_type(2)));
typedef _Float16 f16x4 __attribute__((ext_vector_type(4)));
typedef _Float16 f16x8 __attribute__((ext_vector_type(8)));
typedef float    f32x4 __attribute__((ext_vector_type(4)));
typedef unsigned int uint;

// ---- workspace layout (float units) ----
#define WS_CLS   0
#define CLS_SZ   (BN*NC*HWSZ)
#define WS_REG   (WS_CLS + CLS_SZ)
#define REG_SZ   (BN*2*HWSZ)
#define WS_WH    (WS_REG + REG_SZ)
#define WH_SZ    (BN*2*HWSZ)
#define WS_SC    (WS_WH + WH_SZ)
#define SC_SZ    (BN*HWSZ)
#define WS_CAT   (WS_SC + SC_SZ)
#define CAT_SZ   (BN*HWSZ)
#define WS_W1H   (WS_CAT + CAT_SZ)             // f16 3*9*64*64 -> 55296 floats/plane
#define W1F      (110592/2)
#define WS_W1L   (WS_W1H + W1F)
#define WS_W2H   (WS_W1L + W1F)                // f16 112*64 (padded) -> 3584 floats/plane
#define W2F      (7168/2)
#define WS_W2L   (WS_W2H + W2F)

// scaling: x*16, w*256 -> acc = 4096*true
#define SCL_X   16.0f
#define SCL_W   256.0f
#define INV_ACC (1.0f/4096.0f)

// ---------------------------------------------------------------------------
// Prep: split weights to fp16 hi/lo (scaled by 256).
// w1: [br][s=3dy+dx][co][ci] (B-fragment = contiguous 8 f16, 16B aligned).
// w2: padded 112 rows: [0..79]=cls, [80..81]=reg, [96..97]=wh, rest 0.
// ---------------------------------------------------------------------------
__global__ void k_prep(const float* __restrict__ cw1, const float* __restrict__ rw1,
                       const float* __restrict__ ww1, const float* __restrict__ cw2,
                       const float* __restrict__ rw2, const float* __restrict__ ww2,
                       f16* __restrict__ w1h, f16* __restrict__ w1l,
                       f16* __restrict__ w2h, f16* __restrict__ w2l) {
    int idx = blockIdx.x * 256 + threadIdx.x;
    if (idx < 3*9*64*64) {
        int ci = idx & 63, co = (idx >> 6) & 63;
        int s  = (idx >> 12) % 9, br = idx / 36864;
        const float* src = (br == 0) ? cw1 : (br == 1 ? rw1 : ww1);
        float v = src[(co*64 + ci)*9 + s] * SCL_W;
        f16 h = (f16)v;
        w1h[idx] = h; w1l[idx] = (f16)(v - (float)h);
    }
    int j = idx - 3*9*64*64;
    if (j >= 0 && j < 112*64) {
        int ci = j & 63, row = j >> 6;
        float v = 0.f;
        if (row < 80)                    v = cw2[row*64 + ci];
        else if (row < 82)               v = rw2[(row-80)*64 + ci];
        else if (row >= 96 && row < 98)  v = ww2[(row-96)*64 + ci];
        v *= SCL_W;
        f16 h = (f16)v;
        w2h[j] = h; w2l[j] = (f16)(v - (float)h);
    }
}

// ---------------------------------------------------------------------------
// Fused MFMA conv. grid (y=128, b=16), block 256 (4 waves; wave w: px[32w,32w+32)).
// r6 post-mortem: MfmaUtil 9% — barrier/staging-bound (54 B-restages, 120
// barriers, 8-way b16 write conflicts, 96 acc regs -> 1 wave/SIMD).
// This round: B-fragments load DIRECTLY from global (L2-resident, no LDS, no
// barriers); branch-outer (acc 96->32 regs); double-buffered A row staging
// (1 barrier/stage, 72 MFMAs between barriers); stride-36 A layout with f16x2
// writes (4-way) and b64 frag reads (2-way, free).
// ---------------------------------------------------------------------------
#define APLANE 9360          // 130 rows * 36 f16 * 2 B
#define AWORDS (APLANE/4)
__global__ __launch_bounds__(256) void k_conv(
    const float* __restrict__ x,
    const f16* __restrict__ w1h, const f16* __restrict__ w1l,
    const f16* __restrict__ w2h, const f16* __restrict__ w2l,
    const float* __restrict__ b1c, const float* __restrict__ b1r, const float* __restrict__ b1w,
    const float* __restrict__ b2c, const float* __restrict__ b2r, const float* __restrict__ b2w,
    float* __restrict__ cls_o, float* __restrict__ reg_o, float* __restrict__ wh_o)
{
    __shared__ char smem[37440] __attribute__((aligned(16)));
    // conv1 phase: A buffers [bufi]{hi,lo}: rows 0..129 (px+1), stride 36 f16
    // epilogue phase (aliases): Rh [128][72] f16, Rl at +18432
    f16* Rh = (f16*)smem;
    f16* Rl = (f16*)(smem + 18432);

    const int y = blockIdx.x, b = blockIdx.y;
    const int tid = threadIdx.x;
    const int w = tid >> 6, lane = tid & 63;
    const int l15 = lane & 15, quad = lane >> 4;
    const int wbase = w * 32;

    static const int CS[6] = {0,0,0,1,1,1};
    static const int RS[6] = {0,1,2,0,1,2};

    #define STAGE(bufi, si_) do {                                             \
        int gy = y - 1 + RS[si_];                                             \
        bool ok = (gy >= 0) && (gy < 128);                                    \
        const float* xp = x + ((size_t)(b*64 + CS[si_]*32)*128 + gy)*128;     \
        f16x2* dh = (f16x2*)(smem + (bufi)*2*APLANE);                         \
        f16x2* dl = (f16x2*)(smem + (bufi)*2*APLANE + APLANE);                \
        _Pragma("unroll")                                                     \
        for (int e0 = 0; e0 < 2048; e0 += 256) {                              \
            int e = e0 + tid;                                                 \
            int px = e & 127, cp = e >> 7;                                    \
            float v0 = 0.f, v1 = 0.f;                                         \
            if (ok) { v0 = xp[(size_t)(2*cp)*HWSZ + px]*SCL_X;                \
                      v1 = xp[(size_t)(2*cp+1)*HWSZ + px]*SCL_X; }            \
            f16 h0 = (f16)v0, h1 = (f16)v1;                                   \
            f16 l0 = (f16)(v0 - (float)h0), l1 = (f16)(v1 - (float)h1);       \
            int wi = (px + 1)*18 + cp;                                        \
            dh[wi] = (f16x2){h0, h1};                                         \
            dl[wi] = (f16x2){l0, l1};                                         \
        }                                                                     \
    } while (0)

    #pragma unroll
    for (int br = 0; br < 3; br++) {
        __syncthreads();                     // protect prior R reads / A reuse
        // zero guard rows (px slots 0,129) of all 4 A planes (R phase corrupts)
        if (tid < 144) {
            int plane = tid / 36, rem = tid % 36;
            int row = (rem < 18) ? 0 : 129, wv = rem % 18;
            ((uint*)smem)[plane*AWORDS + row*18 + wv] = 0u;
        }
        f32x4 acc[2][4];
        #pragma unroll
        for (int m = 0; m < 2; m++)
            #pragma unroll
            for (int n = 0; n < 4; n++) acc[m][n] = (f32x4){0.f,0.f,0.f,0.f};

        STAGE(0, 0);
        __syncthreads();
        for (int si = 0; si < 6; si++) {
            int cur = si & 1;
            if (si < 5) STAGE(cur ^ 1, si + 1);
            // ---- compute on buffer cur ----
            {
                const f16* APh = (const f16*)(smem + cur*2*APLANE);
                const f16* APl = (const f16*)(smem + cur*2*APLANE + APLANE);
                const int chunk = CS[si], r = RS[si];
                #pragma unroll
                for (int dx = 0; dx < 3; dx++) {
                    const int s = r*3 + dx;
                    f16x8 ah[2], al[2];
                    #pragma unroll
                    for (int m = 0; m < 2; m++) {
                        int off = (wbase + m*16 + l15 + dx)*36 + quad*8;
                        f16x4 h0 = *(const f16x4*)(APh + off);
                        f16x4 h1 = *(const f16x4*)(APh + off + 4);
                        f16x4 u0 = *(const f16x4*)(APl + off);
                        f16x4 u1 = *(const f16x4*)(APl + off + 4);
                        ah[m] = __builtin_shufflevector(h0, h1, 0,1,2,3,4,5,6,7);
                        al[m] = __builtin_shufflevector(u0, u1, 0,1,2,3,4,5,6,7);
                    }
                    const f16* gbh = w1h + ((size_t)((br*9 + s)*64 + l15))*64 + chunk*32 + quad*8;
                    const f16* gbl = w1l + ((size_t)((br*9 + s)*64 + l15))*64 + chunk*32 + quad*8;
                    #pragma unroll
                    for (int n = 0; n < 4; n++) {
                        f16x8 bh = *(const f16x8*)(gbh + n*1024);
                        f16x8 bl = *(const f16x8*)(gbl + n*1024);
                        #pragma unroll
                        for (int m = 0; m < 2; m++) {
                            acc[m][n] = __builtin_amdgcn_mfma_f32_16x16x32_f16(ah[m], bh, acc[m][n], 0,0,0);
                            acc[m][n] = __builtin_amdgcn_mfma_f32_16x16x32_f16(ah[m], bl, acc[m][n], 0,0,0);
                            acc[m][n] = __builtin_amdgcn_mfma_f32_16x16x32_f16(al[m], bh, acc[m][n], 0,0,0);
                        }
                    }
                }
            }
            __syncthreads();
        }

        // ---- epilogue: bias+ReLU -> R (C-layout -> A-layout), conv2, store ----
        const float* b1 = (br == 0) ? b1c : (br == 1 ? b1r : b1w);
        float b1v[4];
        #pragma unroll
        for (int n = 0; n < 4; n++) b1v[n] = b1[n*16 + l15];
        #pragma unroll
        for (int m = 0; m < 2; m++)
            #pragma unroll
            for (int n = 0; n < 4; n++)
                #pragma unroll
                for (int rg = 0; rg < 4; rg++) {
                    float t = fmaxf(acc[m][n][rg]*INV_ACC + b1v[n], 0.f) * SCL_X;
                    f16 h = (f16)t;
                    int px = wbase + m*16 + quad*4 + rg;
                    int co = n*16 + l15;
                    Rh[px*72 + co] = h;
                    Rl[px*72 + co] = (f16)(t - (float)h);
                }
        __syncthreads();

        const int NT     = (br == 0) ? 5 : 1;
        const int rowoff = (br == 0) ? 0 : (br == 1 ? 80 : 96);
        f32x4 a2[5][2];
        #pragma unroll
        for (int n = 0; n < 5; n++)
            #pragma unroll
            for (int m = 0; m < 2; m++) a2[n][m] = (f32x4){0.f,0.f,0.f,0.f};

        #pragma unroll
        for (int kc = 0; kc < 64; kc += 32) {
            f16x8 xh[2], xl[2];
            #pragma unroll
            for (int m = 0; m < 2; m++) {
                int off = (wbase + m*16 + l15)*72 + kc + quad*8;
                f16x4 h0 = *(const f16x4*)(Rh + off);
                f16x4 h1 = *(const f16x4*)(Rh + off + 4);
                f16x4 u0 = *(const f16x4*)(Rl + off);
                f16x4 u1 = *(const f16x4*)(Rl + off + 4);
                xh[m] = __builtin_shufflevector(h0, h1, 0,1,2,3,4,5,6,7);
                xl[m] = __builtin_shufflevector(u0, u1, 0,1,2,3,4,5,6,7);
            }
            #pragma unroll
            for (int n = 0; n < 5; n++) {
                if (n >= NT) break;
                const f16* g2h = w2h + (rowoff + n*16 + l15)*64 + kc + quad*8;
                const f16* g2l = w2l + (rowoff + n*16 + l15)*64 + kc + quad*8;
                f16x8 bh = *(const f16x8*)g2h;
                f16x8 bl = *(const f16x8*)g2l;
                #pragma unroll
                for (int m = 0; m < 2; m++) {
                    a2[n][m] = __builtin_amdgcn_mfma_f32_16x16x32_f16(xh[m], bh, a2[n][m], 0,0,0);
                    a2[n][m] = __builtin_amdgcn_mfma_f32_16x16x32_f16(xh[m], bl, a2[n][m], 0,0,0);
                    a2[n][m] = __builtin_amdgcn_mfma_f32_16x16x32_f16(xl[m], bh, a2[n][m], 0,0,0);
                }
            }
        }

        if (br == 0) {
            #pragma unroll
            for (int n = 0; n < 5; n++) {
                int co2 = n*16 + l15;
                float bb = b2c[co2];
                #pragma unroll
                for (int m = 0; m < 2; m++)
                    #pragma unroll
                    for (int rg = 0; rg < 4; rg++) {
                        float sv = a2[n][m][rg]*INV_ACC + bb;
                        int px = wbase + m*16 + quad*4 + rg;
                        cls_o[((size_t)(b*80 + co2)*128 + y)*128 + px] = 1.f/(1.f + expf(-sv));
                    }
            }
        } else {
            if (l15 < 2) {
                const float* b2 = (br == 1) ? b2r : b2w;
                float* outp     = (br == 1) ? reg_o : wh_o;
                float bb = b2[l15];
                #pragma unroll
                for (int m = 0; m < 2; m++)
                    #pragma unroll
                    for (int rg = 0; rg < 4; rg++) {
                        float sv = a2[0][m][rg]*INV_ACC + bb;
                        float o  = (br == 1) ? (1.f/(1.f + expf(-sv))) : expf(sv);
                        int px = wbase + m*16 + quad*4 + rg;
                        outp[((size_t)(b*2 + l15)*128 + y)*128 + px] = o;
                    }
            }
        }
    }
    #undef STAGE
}

// ---------------------------------------------------------------------------
// 3x3 peak mask + max/argmax over classes — barrier-free (r5, verified).
// ---------------------------------------------------------------------------
__global__ __launch_bounds__(256) void k_peaks(const float* __restrict__ cls,
                                               float* __restrict__ sc,
                                               int* __restrict__ cat) {
    const int b  = blockIdx.y;
    const int wv = threadIdx.x >> 6;
    const int l  = threadIdx.x & 63;
    const int y  = blockIdx.x * 4 + wv;
    const int p0 = l * 2;
    const bool yt = (y > 0), yb = (y < 127);
    float best0 = -1.f, best1 = -1.f;
    int bc0 = 0, bc1 = 0;
    for (int c = 0; c < 80; c++) {
        const float* pl = cls + (size_t)(b*80 + c)*HWSZ + y*128 + p0;
        float2 cur = *(const float2*)pl;
        float2 tp  = yt ? *(const float2*)(pl - 128) : make_float2(-1e30f, -1e30f);
        float2 bt  = yb ? *(const float2*)(pl + 128) : make_float2(-1e30f, -1e30f);
        float vm0 = fmaxf(cur.x, fmaxf(tp.x, bt.x));
        float vm1 = fmaxf(cur.y, fmaxf(tp.y, bt.y));
        float lft = __shfl_up(vm1, 1);   if (l == 0)  lft = -1e30f;
        float rgt = __shfl_down(vm0, 1); if (l == 63) rgt = -1e30f;
        float m0 = fmaxf(lft, fmaxf(vm0, vm1));
        float m1 = fmaxf(vm0, fmaxf(vm1, rgt));
        float k0 = (cur.x == m0) ? cur.x : 0.f;
        float k1 = (cur.y == m1) ? cur.y : 0.f;
        if (k0 > best0) { best0 = k0; bc0 = c; }   // strict > == first-max
        if (k1 > best1) { best1 = k1; bc1 = c; }
    }
    int o = b*HWSZ + y*128 + p0;
    *(float2*)&sc[o] = make_float2(best0, best1);
    *(int2*)&cat[o]  = make_int2(bc0, bc1);
}

// ---------------------------------------------------------------------------
// Fused per-batch top-100 + box decode + NMS + all outputs (r5, verified).
// ---------------------------------------------------------------------------
__global__ void k_select(float* __restrict__ sc, const int* __restrict__ cats,
                         const float* __restrict__ regp, const float* __restrict__ whp,
                         float* __restrict__ out) {
    const int b   = blockIdx.x;
    const int tid = threadIdx.x;
    float* scb = sc + (size_t)b*HWSZ;

    __shared__ float cmax[64];
    __shared__ int   cidx[64];
    __shared__ int   s_inds[KK];
    __shared__ float s_vals[KK];
    __shared__ float X1[KK], Y1[KK], X2[KK], Y2[KK], AR[KK];

    {   // Phase A: per-chunk max (value desc, first index)
        int c = tid >> 2, q = tid & 3;
        int base = c*256 + q*64;
        float bv = -1e30f; int bi = base;
        for (int e = 0; e < 64; e++) {
            float v = scb[base + e];
            if (v > bv) { bv = v; bi = base + e; }
        }
        #pragma unroll
        for (int off = 1; off <= 2; off <<= 1) {
            float ov = __shfl_xor(bv, off);
            int   oi = __shfl_xor(bi, off);
            if (ov > bv || (ov == bv && oi < bi)) { bv = ov; bi = oi; }
        }
        if (q == 0) { cmax[c] = bv; cidx[c] = bi; }
    }
    __syncthreads();

    if (tid < 64) {  // Phase B: 100 selections, wave 0
        const int l = tid;
        float v = cmax[l]; int ix = cidx[l];
        for (int it = 0; it < KK; it++) {
            float rv = v; int ri = ix;
            #pragma unroll
            for (int off = 32; off >= 1; off >>= 1) {
                float ov = __shfl_down(rv, off);
                int   oi = __shfl_down(ri, off);
                if (ov > rv || (ov == rv && oi < ri)) { rv = ov; ri = oi; }
            }
            float fv = __shfl(rv, 0);
            int   fi = __shfl(ri, 0);
            if (l == 0) { s_inds[it] = fi; s_vals[it] = fv; scb[fi] = -1e30f; }
            int wc = fi >> 8;
            int eb = wc*256 + l*4;
            float nv = -1e30f; int ni = eb;
            #pragma unroll
            for (int r = 0; r < 4; r++) {
                float u = scb[eb + r];
                if (u > nv) { nv = u; ni = eb + r; }
            }
            #pragma unroll
            for (int off = 32; off >= 1; off >>= 1) {
                float ov = __shfl_down(nv, off);
                int   oi = __shfl_down(ni, off);
                if (ov > nv || (ov == nv && oi < ni)) { nv = ov; ni = oi; }
            }
            float cv = __shfl(nv, 0);
            int   ci2 = __shfl(ni, 0);
            if (l == wc) { v = cv; ix = ci2; }
        }
    }
    __syncthreads();

    if (tid < KK) {  // Phase C: decode boxes
        int ind   = s_inds[tid];
        float scv = s_vals[tid];
        const float* rb = regp + (size_t)b*2*HWSZ;
        const float* wb = whp  + (size_t)b*2*HWSZ;
        float r0 = rb[ind], r1 = rb[HWSZ + ind];
        float w0 = wb[ind], w1 = wb[HWSZ + ind];
        float ctx = (float)(ind & 127) + r0;
        float cty = (float)(ind >> 7) + r1;
        float x1 = (ctx - w0*0.5f)*4.f, y1 = (cty - w1*0.5f)*4.f;
        float x2 = (ctx + w0*0.5f)*4.f, y2 = (cty + w1*0.5f)*4.f;
        size_t bo = ((size_t)b*KK + tid)*4;
        out[bo+0] = x1; out[bo+1] = y1; out[bo+2] = x2; out[bo+3] = y2;
        out[BN*KK*4 + b*KK + tid]         = (float)cats[(size_t)b*HWSZ + ind];
        out[BN*KK*4 + BN*KK + b*KK + tid] = scv;
        X1[tid] = x1; Y1[tid] = y1; X2[tid] = x2; Y2[tid] = y2;
        AR[tid] = (x2 - x1)*(y2 - y1);
    }
    __syncthreads();

    if (tid < 64) {  // Phase D: NMS in wave 0
        const int l = tid;
        float x1a = X1[l], y1a = Y1[l], x2a = X2[l], y2a = Y2[l], ara = AR[l];
        int   ka  = (s_vals[l] > 0.2f) ? 1 : 0;
        float x1b = 0, y1b = 0, x2b = 0, y2b = 0, arb = 0;
        int   kb  = 0;
        if (l < KK - 64) {
            x1b = X1[64+l]; y1b = Y1[64+l]; x2b = X2[64+l]; y2b = Y2[64+l];
            arb = AR[64+l];
            kb  = (s_vals[64+l] > 0.2f) ? 1 : 0;
        }
        for (int i = 0; i < KK; i++) {
            float jx1, jy1, jx2, jy2, jar; int jk;
            if (i < 64) {
                jx1 = __shfl(x1a, i); jy1 = __shfl(y1a, i);
                jx2 = __shfl(x2a, i); jy2 = __shfl(y2a, i);
                jar = __shfl(ara, i); jk  = __shfl(ka,  i);
            } else {
                int li = i - 64;
                jx1 = __shfl(x1b, li); jy1 = __shfl(y1b, li);
                jx2 = __shfl(x2b, li); jy2 = __shfl(y2b, li);
                jar = __shfl(arb, li); jk  = __shfl(kb,  li);
            }
            if (jk) {
                if (ka && l > i) {
                    float iw = fminf(jx2, x2a) - fmaxf(jx1, x1a); iw = iw > 0.f ? iw : 0.f;
                    float ih = fminf(jy2, y2a) - fmaxf(jy1, y1a); ih = ih > 0.f ? ih : 0.f;
                    float inter = iw*ih;
                    float iou = inter / (jar + ara - inter + 1e-9f);
                    if (iou > 0.5f) ka = 0;
                }
                if (kb && (64 + l) > i) {
                    float iw = fminf(jx2, x2b) - fmaxf(jx1, x1b); iw = iw > 0.f ? iw : 0.f;
                    float ih = fminf(jy2, y2b) - fmaxf(jy1, y1b); ih = ih > 0.f ? ih : 0.f;
                    float inter = iw*ih;
                    float iou = inter / (jar + arb - inter + 1e-9f);
                    if (iou > 0.5f) kb = 0;
                }
            }
        }
        int koff = BN*KK*4 + 2*BN*KK;
        out[koff + b*KK + l] = ka ? 1.f : 0.f;
        if (l < KK - 64) out[koff + b*KK + 64 + l] = kb ? 1.f : 0.f;
    }
}

// ---------------------------------------------------------------------------
extern "C" void kernel_launch(void* const* d_in, const int* in_sizes, int n_in,
                              void* d_out, int out_size, void* d_ws, size_t ws_size,
                              hipStream_t stream) {
    const float* x      = (const float*)d_in[0];
    const float* cls_w1 = (const float*)d_in[1];
    const float* cls_b1 = (const float*)d_in[2];
    const float* cls_w2 = (const float*)d_in[3];
    const float* cls_b2 = (const float*)d_in[4];
    const float* reg_w1 = (const float*)d_in[5];
    const float* reg_b1 = (const float*)d_in[6];
    const float* reg_w2 = (const float*)d_in[7];
    const float* reg_b2 = (const float*)d_in[8];
    const float* wh_w1  = (const float*)d_in[9];
    const float* wh_b1  = (const float*)d_in[10];
    const float* wh_w2  = (const float*)d_in[11];
    const float* wh_b2  = (const float*)d_in[12];

    float* ws   = (float*)d_ws;
    float* clsb = ws + WS_CLS;
    float* regb = ws + WS_REG;
    float* whb  = ws + WS_WH;
    float* scw  = ws + WS_SC;
    int*   cat  = (int*)(ws + WS_CAT);
    f16*   w1h  = (f16*)(ws + WS_W1H);
    f16*   w1l  = (f16*)(ws + WS_W1L);
    f16*   w2h  = (f16*)(ws + WS_W2H);
    f16*   w2l  = (f16*)(ws + WS_W2L);
    float* out  = (float*)d_out;

    k_prep<<<(3*9*64*64 + 112*64 + 255)/256, 256, 0, stream>>>(
        cls_w1, reg_w1, wh_w1, cls_w2, reg_w2, wh_w2, w1h, w1l, w2h, w2l);
    k_conv<<<dim3(128, 16), 256, 0, stream>>>(
        x, w1h, w1l, w2h, w2l, cls_b1, reg_b1, wh_b1,
        cls_b2, reg_b2, wh_b2, clsb, regb, whb);
    k_peaks<<<dim3(32, 16), 256, 0, stream>>>(clsb, scw, cat);
    k_select<<<16, 256, 0, stream>>>(scw, cat, regb, whb, out);
}